// Round 1
// baseline (5028.297 us; speedup 1.0000x reference)
//
#include <hip/hip_runtime.h>

typedef _Float16 h8 __attribute__((ext_vector_type(8)));
typedef _Float16 h4 __attribute__((ext_vector_type(4)));
typedef float    f4 __attribute__((ext_vector_type(4)));

#define NBATCH 64
#define NT     512
#define NHID   512
#define OUT0   33554432   // 64*512*1024

__device__ __forceinline__ float sigm(float x)  { return 1.0f / (1.0f + __expf(-x)); }
__device__ __forceinline__ float tanhf_(float x){ float e = __expf(2.0f * x); return 1.0f - 2.0f / (e + 1.0f); }

// ---------------- prep kernels ----------------

__global__ __launch_bounds__(256) void xconv_k(const float* __restrict__ x, _Float16* __restrict__ x16) {
    size_t i = ((size_t)blockIdx.x * 256 + threadIdx.x) * 4;
    f4 v = *(const f4*)(x + i);
    h4 o; o[0] = (_Float16)v[0]; o[1] = (_Float16)v[1]; o[2] = (_Float16)v[2]; o[3] = (_Float16)v[3];
    *(h4*)(x16 + i) = o;
}

// wcat16[dir][p][k], p = j*4 + gate (j in [0,512), gate in {i,f,g,o}), k in [0,1024): k<512 -> Wih, else Whh
__global__ __launch_bounds__(256) void wconv_k(const float* __restrict__ Wih_f, const float* __restrict__ Whh_f,
                                               const float* __restrict__ Wih_b, const float* __restrict__ Whh_b,
                                               _Float16* __restrict__ wcat) {
    size_t e = (size_t)blockIdx.x * 256 + threadIdx.x;   // 2*2048*256 total
    int k4  = (int)(e & 255);
    int p   = (int)((e >> 8) & 2047);
    int dir = (int)(e >> 19);
    int gate = p & 3, j = p >> 2;
    int k = k4 * 4;
    const float* Wih = dir ? Wih_b : Wih_f;
    const float* Whh = dir ? Whh_b : Whh_f;
    f4 v;
    if (k < 512) v = *(const f4*)&Wih[((size_t)gate * 512 + j) * 512 + k];
    else         v = *(const f4*)&Whh[((size_t)gate * 512 + j) * 512 + (k - 512)];
    h4 o; o[0] = (_Float16)v[0]; o[1] = (_Float16)v[1]; o[2] = (_Float16)v[2]; o[3] = (_Float16)v[3];
    *(h4*)&wcat[(((size_t)dir * 2048) + p) * 1024 + k] = o;
}

template<bool USE16>
__global__ __launch_bounds__(256) void init_k(const float* __restrict__ enc_h, const float* __restrict__ enc_c,
                                              float* __restrict__ hseg, float* __restrict__ cseg,
                                              _Float16* __restrict__ h16a, float* __restrict__ hfa) {
    int e = blockIdx.x * 256 + threadIdx.x;   // 0..131071
    if (e < 65536) {
        float v = enc_h[e];
        hseg[e] = v;
        if (USE16) {
            int b = e >> 10, q = e & 1023;
            int dir = q >> 9, j = q & 511;
            h16a[((size_t)(dir * 64 + b)) * 512 + j] = (_Float16)v;
        } else {
            hfa[e] = v;
        }
    } else {
        int e2 = e - 65536;
        cseg[e2] = enc_c[e2];
    }
}

// ---------------- per-timestep fused kernel ----------------
// grid (128, 2): blockIdx.x -> 4 h-dims (16 gate rows), blockIdx.y = dir.
// Block: 256 thr = 4 waves, wave w = batch M-tile [16w,16w+16). N-tile = 16 gate rows.
// K=1024 staged in 8 chunks of 128 through LDS; mfma_f32_16x16x32_f16.
template<bool USE16>
__global__ __launch_bounds__(256) void lstm_step(
    const float* __restrict__ xin, const _Float16* __restrict__ x16, const _Float16* __restrict__ wcat,
    const float* __restrict__ Wih_f, const float* __restrict__ Whh_f,
    const float* __restrict__ Wih_b, const float* __restrict__ Whh_b,
    const float* __restrict__ b_f, const float* __restrict__ b_b,
    const _Float16* __restrict__ h16r, _Float16* __restrict__ h16w,
    const float* __restrict__ hfr, float* __restrict__ hfw,
    float* __restrict__ out, float* __restrict__ hseg, float* __restrict__ cseg, int t) {

    const int dir = blockIdx.y;
    const int bx  = blockIdx.x;        // 0..127
    const int j0  = bx * 4;
    const int p0  = bx * 16;
    const int tid = threadIdx.x;
    const int lane = tid & 63;
    const int wv   = tid >> 6;         // M-tile id
    const int tx   = dir ? (NT - 1 - t) : t;   // x time index == output time index

    __shared__ __align__(16) _Float16 zs[64][136];   // z chunk [batch][128], +8 pad (row stride 272B = 17*16)
    __shared__ __align__(16) _Float16 wsh[16][136];  // W chunk [n][128]
    __shared__ float gbuf[64][17];

    f4 acc = {0.f, 0.f, 0.f, 0.f};
    const int m0   = wv * 16;
    const int arow = m0 + (lane & 15);
    const int koff = (lane >> 4) * 8;
    const int brow = lane & 15;
    const float* bias = dir ? b_b : b_f;

    for (int ch = 0; ch < 8; ++ch) {
        const int kb = ch * 128;
        // ---- stage z chunk [64 x 128] (chunks 0-3: x_t; 4-7: h) ----
        if (ch < 4) {
            if (USE16) {
                #pragma unroll
                for (int it = 0; it < 4; ++it) {
                    int e = tid + 256 * it;          // 0..1023
                    int r = e >> 4, c8 = e & 15;
                    h8 v = *(const h8*)&x16[((size_t)r * NT + tx) * 512 + kb + c8 * 8];
                    *(h8*)&zs[r][c8 * 8] = v;
                }
            } else {
                #pragma unroll
                for (int it = 0; it < 8; ++it) {
                    int e = tid + 256 * it;          // 0..2047
                    int r = e >> 5, c4 = e & 31;
                    f4 v = *(const f4*)&xin[((size_t)r * NT + tx) * 512 + kb + c4 * 4];
                    h4 o; o[0] = (_Float16)v[0]; o[1] = (_Float16)v[1]; o[2] = (_Float16)v[2]; o[3] = (_Float16)v[3];
                    *(h4*)&zs[r][c4 * 4] = o;
                }
            }
        } else {
            const int kh = kb - 512;
            if (USE16) {
                #pragma unroll
                for (int it = 0; it < 4; ++it) {
                    int e = tid + 256 * it;
                    int r = e >> 4, c8 = e & 15;
                    h8 v = *(const h8*)&h16r[((size_t)(dir * 64 + r)) * 512 + kh + c8 * 8];
                    *(h8*)&zs[r][c8 * 8] = v;
                }
            } else {
                #pragma unroll
                for (int it = 0; it < 8; ++it) {
                    int e = tid + 256 * it;
                    int r = e >> 5, c4 = e & 31;
                    f4 v = *(const f4*)&hfr[(size_t)r * 1024 + dir * 512 + kh + c4 * 4];
                    h4 o; o[0] = (_Float16)v[0]; o[1] = (_Float16)v[1]; o[2] = (_Float16)v[2]; o[3] = (_Float16)v[3];
                    *(h4*)&zs[r][c4 * 4] = o;
                }
            }
        }
        // ---- stage W chunk [16 x 128] ----
        if (USE16) {
            int r = tid >> 4, c8 = tid & 15;
            h8 v = *(const h8*)&wcat[(((size_t)dir * 2048) + p0 + r) * 1024 + kb + c8 * 8];
            *(h8*)&wsh[r][c8 * 8] = v;
        } else {
            const float* Wih = dir ? Wih_b : Wih_f;
            const float* Whh = dir ? Whh_b : Whh_f;
            #pragma unroll
            for (int it = 0; it < 2; ++it) {
                int e = tid + 256 * it;              // 0..511
                int r = e >> 5, c4 = e & 31;
                int gate = r & 3, j = j0 + (r >> 2);
                int k = kb + c4 * 4;
                f4 v;
                if (k < 512) v = *(const f4*)&Wih[((size_t)gate * 512 + j) * 512 + k];
                else         v = *(const f4*)&Whh[((size_t)gate * 512 + j) * 512 + (k - 512)];
                h4 o; o[0] = (_Float16)v[0]; o[1] = (_Float16)v[1]; o[2] = (_Float16)v[2]; o[3] = (_Float16)v[3];
                *(h4*)&wsh[r][c4 * 4] = o;
            }
        }
        __syncthreads();
        // ---- MFMA over 4 k-tiles of 32 ----
        #pragma unroll
        for (int kt = 0; kt < 4; ++kt) {
            h8 a = *(const h8*)&zs[arow][kt * 32 + koff];
            h8 b = *(const h8*)&wsh[brow][kt * 32 + koff];
            acc = __builtin_amdgcn_mfma_f32_16x16x32_f16(a, b, acc, 0, 0, 0);
        }
        __syncthreads();
    }

    // ---- epilogue: bias + exchange via LDS ----
    {
        int n = lane & 15;
        int gate = n & 3, jj = n >> 2;
        float bn = bias[gate * 512 + j0 + jj];
        int mrow = m0 + (lane >> 4) * 4;
        #pragma unroll
        for (int r = 0; r < 4; ++r)
            gbuf[mrow + r][n] = acc[r] + bn;   // D layout: col = lane&15, row = (lane>>4)*4 + r
    }
    __syncthreads();
    {
        int m = tid >> 2;        // batch
        int jj = tid & 3;
        float gi = gbuf[m][jj * 4 + 0];
        float gf = gbuf[m][jj * 4 + 1];
        float gg = gbuf[m][jj * 4 + 2];
        float go = gbuf[m][jj * 4 + 3];
        float i_ = sigm(gi), f_ = sigm(gf), o_ = sigm(go);
        float g_ = tanhf_(gg);
        int j = j0 + jj;
        size_t sidx = (size_t)m * 1024 + dir * 512 + j;
        float c_old = cseg[sidx];
        float c_new = f_ * c_old + i_ * g_;
        cseg[sidx] = c_new;
        float h = o_ * tanhf_(c_new);
        hseg[sidx] = h;                                   // running final-h (last step wins)
        if (USE16) h16w[((size_t)(dir * 64 + m)) * 512 + j] = (_Float16)h;
        else       hfw[sidx] = h;
        out[((size_t)m * NT + tx) * 1024 + dir * 512 + j] = h;
    }
}

// ---------------- launcher ----------------

extern "C" void kernel_launch(void* const* d_in, const int* in_sizes, int n_in,
                              void* d_out, int out_size, void* d_ws, size_t ws_size,
                              hipStream_t stream) {
    const float* xin   = (const float*)d_in[0];
    const float* enc_h = (const float*)d_in[1];
    const float* enc_c = (const float*)d_in[2];
    const float* Wih_f = (const float*)d_in[3];
    const float* Whh_f = (const float*)d_in[4];
    const float* b_f   = (const float*)d_in[5];
    const float* Wih_b = (const float*)d_in[6];
    const float* Whh_b = (const float*)d_in[7];
    const float* b_b   = (const float*)d_in[8];

    float* out  = (float*)d_out;
    float* hseg = out + OUT0;          // final h [64,1024]
    float* cseg = hseg + 65536;        // final c [64,1024]

    const size_t X16_BYTES  = (size_t)64 * 512 * 512 * 2;        // 33,554,432
    const size_t WCAT_BYTES = (size_t)2 * 2048 * 1024 * 2;       //  8,388,608
    const size_t H16_BYTES  = (size_t)2 * 64 * 512 * 2;          //    131,072
    const bool use16 = ws_size >= (X16_BYTES + WCAT_BYTES + 2 * H16_BYTES);

    if (use16) {
        _Float16* x16  = (_Float16*)d_ws;
        _Float16* wcat = (_Float16*)((char*)d_ws + X16_BYTES);
        _Float16* h16a = (_Float16*)((char*)d_ws + X16_BYTES + WCAT_BYTES);
        _Float16* h16b = (_Float16*)((char*)d_ws + X16_BYTES + WCAT_BYTES + H16_BYTES);

        xconv_k<<<dim3(16384), dim3(256), 0, stream>>>(xin, x16);
        wconv_k<<<dim3(4096), dim3(256), 0, stream>>>(Wih_f, Whh_f, Wih_b, Whh_b, wcat);
        init_k<true><<<dim3(512), dim3(256), 0, stream>>>(enc_h, enc_c, hseg, cseg, h16a, nullptr);
        for (int t = 0; t < 512; ++t) {
            const _Float16* hr = (t & 1) ? h16b : h16a;
            _Float16*       hw = (t & 1) ? h16a : h16b;
            lstm_step<true><<<dim3(128, 2), dim3(256), 0, stream>>>(
                xin, x16, wcat, Wih_f, Whh_f, Wih_b, Whh_b, b_f, b_b,
                hr, hw, nullptr, nullptr, out, hseg, cseg, t);
        }
    } else {
        float* hfa = (float*)d_ws;                     // [64,1024] fp32 ping
        float* hfb = hfa + 65536;                      // pong
        init_k<false><<<dim3(512), dim3(256), 0, stream>>>(enc_h, enc_c, hseg, cseg, nullptr, hfa);
        for (int t = 0; t < 512; ++t) {
            const float* hr = (t & 1) ? hfb : hfa;
            float*       hw = (t & 1) ? hfa : hfb;
            lstm_step<false><<<dim3(128, 2), dim3(256), 0, stream>>>(
                xin, nullptr, nullptr, Wih_f, Whh_f, Wih_b, Whh_b, b_f, b_b,
                nullptr, nullptr, hr, hw, out, hseg, cseg, t);
        }
    }
}